// Round 11
// baseline (261.400 us; speedup 1.0000x reference)
//
#include <hip/hip_runtime.h>

// ---------------------------------------------------------------------------
// GCN: x1 = relu(Ahat @ (fts@W1) + b1); x2 = relu(Ahat @ (x1@W2) + b2);
//      out = x2@Wc + bc.  Ahat = D^-1/2 (A + I) D^-1/2.
// d_out = [out (N*16) | x2 (N*128)] fp32.
// R2: hierarchical scan. R3: gather prescale+unroll. R4: MFMA fp16 GEMMs.
// R5/R6: slot-capture CSR build. R7: 8-replica counters. R8: launch diet.
// R9: barrier-free agg, 16 lanes/row dwordx4 gathers, shfl_xor combine.
// R10 FAILED: persistent fused graph build ran at 1 wave/SIMD (130us).
// R11: split graph build restored; CLS fusion kept (+12us epilogue tax).
// R12: epilogue diet (hoisted operands, LDS WcT, 2-shfl reduce): agg2 53->48.
// R13: v_fma_mix accumulate (1 VALU/elem) + col prefetch: agg2 48.4->47.4.
// R14/15 FAILED: persistent strided agg: occupancy 67->39%, agg2 +2us.
// R16: NPW=4 consecutive + tail unroll-2: agg2 47.4->42.0, agg1 +5us.
// R17: NPW per-kernel: agg1 NPW=1, agg2 NPW=4. BEST: 257.0us.
// R18/19 FAILED: balanced exact-fit 8192-wave split: agg2 42->47,
//      occupancy 51->39%. CONFIRMED (with R14): time-averaged occupancy
//      dies in the drain tail of static partitions; HW dynamic scheduling
//      of many small blocks wins for irregular work. Revert to NPW=4.
// R20: cross-node software pipeline INSIDE the NPW=4 loop: e0 of node i+1
//      == e1 of node i, so prefetch next node's first col quad + self-row
//      + dinv while current node's gathers are in flight (3 of 4 nodes get
//      head-of-node latency hidden). col padded +16 for speculative quad.
// ---------------------------------------------------------------------------

#define IN_DIM 256
#define HID 128
#define OUT_DIM 16
#define SCAN_B 256
#define NREP 8

typedef _Float16 half8  __attribute__((ext_vector_type(8)));
typedef float    floatx4 __attribute__((ext_vector_type(4)));

// acc[0..7] += fp16 elements of u (4 dwords, lo/hi halves), exact, 1 VALU each.
__device__ __forceinline__ void accum8(float* acc, uint4 u, float onef) {
    asm("v_fma_mix_f32 %0, %1, %2, %0 op_sel:[0,0,0] op_sel_hi:[1,0,0]"
        : "+v"(acc[0]) : "v"(u.x), "v"(onef));
    asm("v_fma_mix_f32 %0, %1, %2, %0 op_sel:[1,0,0] op_sel_hi:[1,0,0]"
        : "+v"(acc[1]) : "v"(u.x), "v"(onef));
    asm("v_fma_mix_f32 %0, %1, %2, %0 op_sel:[0,0,0] op_sel_hi:[1,0,0]"
        : "+v"(acc[2]) : "v"(u.y), "v"(onef));
    asm("v_fma_mix_f32 %0, %1, %2, %0 op_sel:[1,0,0] op_sel_hi:[1,0,0]"
        : "+v"(acc[3]) : "v"(u.y), "v"(onef));
    asm("v_fma_mix_f32 %0, %1, %2, %0 op_sel:[0,0,0] op_sel_hi:[1,0,0]"
        : "+v"(acc[4]) : "v"(u.z), "v"(onef));
    asm("v_fma_mix_f32 %0, %1, %2, %0 op_sel:[1,0,0] op_sel_hi:[1,0,0]"
        : "+v"(acc[5]) : "v"(u.z), "v"(onef));
    asm("v_fma_mix_f32 %0, %1, %2, %0 op_sel:[0,0,0] op_sel_hi:[1,0,0]"
        : "+v"(acc[6]) : "v"(u.w), "v"(onef));
    asm("v_fma_mix_f32 %0, %1, %2, %0 op_sel:[1,0,0] op_sel_hi:[1,0,0]"
        : "+v"(acc[7]) : "v"(u.w), "v"(onef));
}

__device__ __forceinline__ void wswz_one(const float* W, _Float16* Bsw, int o, int permK) {
    int j    = o & 7;
    int lane = (o >> 3) & 63;
    int t    = (o >> 9) & 7;
    int c    = o >> 12;
    int k = c * 32 + ((lane >> 4) << 3) + j;
    if (permK) k = ((k & 7) << 4) + (k >> 3);
    int ncol = t * 16 + (lane & 15);
    Bsw[o] = (_Float16)W[k * 128 + ncol];
}

// Fused prep: zero rep planes; swizzle W1,W2 -> fp16 fragment order; permute biases.
__global__ void k_prep(int* __restrict__ rep, int nrepN,
                       const float* __restrict__ W1, _Float16* __restrict__ Bsw1,
                       const float* __restrict__ W2, _Float16* __restrict__ Bsw2,
                       const float* __restrict__ b1, float* __restrict__ bp1,
                       const float* __restrict__ b2, float* __restrict__ bp2) {
    int t = blockIdx.x * blockDim.x + threadIdx.x;
    int z4 = nrepN >> 2;
    int zr = z4 + (nrepN & 3);
    if (t < z4) { ((int4*)rep)[t] = make_int4(0, 0, 0, 0); return; }
    if (t < zr) { rep[4 * z4 + (t - z4)] = 0; return; }
    int o = t - zr;
    if (o < IN_DIM * HID) { wswz_one(W1, Bsw1, o, 0); return; }
    o -= IN_DIM * HID;
    if (o < HID * HID) { wswz_one(W2, Bsw2, o, 1); return; }
    o -= HID * HID;
    if (o < HID) { bp1[o] = b1[((o & 7) << 4) + (o >> 3)]; return; }
    o -= HID;
    if (o < HID) { bp2[o] = b2[((o & 7) << 4) + (o >> 3)]; return; }
}

// Thread i owns edges 8i..8i+7; edge 8i+k bumps replica plane k.
__global__ void k_count(const int* __restrict__ dst, int* __restrict__ rep,
                        int* __restrict__ slot, int nN, int e8, int e) {
    int i = blockIdx.x * blockDim.x + threadIdx.x;
    if (i < e8) {
        int4 d0 = ((const int4*)dst)[2 * i];
        int4 d1 = ((const int4*)dst)[2 * i + 1];
        int4 s0, s1;
        s0.x = atomicAdd(&rep[0 * nN + d0.x], 1);
        s0.y = atomicAdd(&rep[1 * nN + d0.y], 1);
        s0.z = atomicAdd(&rep[2 * nN + d0.z], 1);
        s0.w = atomicAdd(&rep[3 * nN + d0.w], 1);
        s1.x = atomicAdd(&rep[4 * nN + d1.x], 1);
        s1.y = atomicAdd(&rep[5 * nN + d1.y], 1);
        s1.z = atomicAdd(&rep[6 * nN + d1.z], 1);
        s1.w = atomicAdd(&rep[7 * nN + d1.w], 1);
        ((int4*)slot)[2 * i]     = s0;
        ((int4*)slot)[2 * i + 1] = s1;
    }
    int base = e8 * 8;
    int t = blockIdx.x * blockDim.x + threadIdx.x;
    if (t < e - base) {
        int j = base + t;
        slot[j] = atomicAdd(&rep[(j & 7) * nN + dst[j]], 1);
    }
}

// Planes -> per-node exclusive bases (in-place); node totals -> deg;
// per-block scan of totals; block total -> bsum.
__global__ __launch_bounds__(SCAN_B) void k_scan1(int* __restrict__ rep,
                                                  int* __restrict__ deg,
                                                  int* __restrict__ row_ptr,
                                                  int* __restrict__ bsum,
                                                  int nN, int n) {
    __shared__ int tmp[SCAN_B];
    int tid = threadIdx.x;
    int i = blockIdx.x * SCAN_B + tid;
    int c = 0;
    if (i < n) {
        #pragma unroll
        for (int r = 0; r < NREP; ++r) {
            int t = rep[r * nN + i];
            rep[r * nN + i] = c;
            c += t;
        }
        deg[i] = c;
    }
    tmp[tid] = c;
    __syncthreads();
    #pragma unroll
    for (int off = 1; off < SCAN_B; off <<= 1) {
        int v = (tid >= off) ? tmp[tid - off] : 0;
        __syncthreads();
        tmp[tid] += v;
        __syncthreads();
    }
    if (i < n) row_ptr[i] = tmp[tid] - c;
    if (tid == SCAN_B - 1) bsum[blockIdx.x] = tmp[tid];
}

// Finalize: base = sum(bsum[0..blockIdx-1]); row_ptr/dinv; bake bases into planes.
__global__ __launch_bounds__(SCAN_B) void k_scan3(int* __restrict__ row_ptr,
                                                  const int* __restrict__ bsum,
                                                  const int* __restrict__ deg,
                                                  float* __restrict__ dinv,
                                                  int* __restrict__ rep,
                                                  int nN, int n, int e) {
    __shared__ int red[SCAN_B];
    int tid = threadIdx.x;
    int acc = 0;
    for (int j = tid; j < blockIdx.x; j += SCAN_B) acc += bsum[j];
    red[tid] = acc;
    __syncthreads();
    #pragma unroll
    for (int off = SCAN_B / 2; off >= 1; off >>= 1) {
        if (tid < off) red[tid] += red[tid + off];
        __syncthreads();
    }
    int base = red[0];
    int i = blockIdx.x * SCAN_B + tid;
    if (i < n) {
        int rp = row_ptr[i] + base;
        row_ptr[i] = rp;
        dinv[i] = rsqrtf((float)(deg[i] + 1));   // +1 self-loop
        #pragma unroll
        for (int r = 0; r < NREP; ++r) rep[r * nN + i] += rp;
    }
    if (i == 0) row_ptr[n] = e;
}

// Atomic-free scatter: col[rep[k][dst] + slot] = src.
__global__ void k_fill(const int* __restrict__ src, const int* __restrict__ dst,
                       const int* __restrict__ slot, const int* __restrict__ rep,
                       int* __restrict__ col, int nN, int e8, int e) {
    int i = blockIdx.x * blockDim.x + threadIdx.x;
    if (i < e8) {
        int4 v0 = ((const int4*)src)[2 * i];
        int4 v1 = ((const int4*)src)[2 * i + 1];
        int4 d0 = ((const int4*)dst)[2 * i];
        int4 d1 = ((const int4*)dst)[2 * i + 1];
        int4 s0 = ((const int4*)slot)[2 * i];
        int4 s1 = ((const int4*)slot)[2 * i + 1];
        col[rep[0 * nN + d0.x] + s0.x] = v0.x;
        col[rep[1 * nN + d0.y] + s0.y] = v0.y;
        col[rep[2 * nN + d0.z] + s0.z] = v0.z;
        col[rep[3 * nN + d0.w] + s0.w] = v0.w;
        col[rep[4 * nN + d1.x] + s1.x] = v1.x;
        col[rep[5 * nN + d1.y] + s1.y] = v1.y;
        col[rep[6 * nN + d1.z] + s1.z] = v1.z;
        col[rep[7 * nN + d1.w] + s1.w] = v1.w;
    }
    int base = e8 * 8;
    int t = blockIdx.x * blockDim.x + threadIdx.x;
    if (t < e - base) {
        int j = base + t;
        col[rep[(j & 7) * nN + dst[j]] + slot[j]] = src[j];
    }
}

// Cb[n,128](fp16, pi-permuted cols) = dinv[row] * (A[n,K] @ W[K,128]).
template<bool A32>
__global__ __launch_bounds__(256) void k_gemm_mfma(const void* __restrict__ Av,
                                                   const _Float16* __restrict__ Bsw,
                                                   _Float16* __restrict__ Cb,
                                                   const float* __restrict__ dinv,
                                                   int n, int K) {
    int tid   = threadIdx.x;
    int w     = tid >> 6;
    int ln    = tid & 63;
    int lane16 = ln & 15;
    int quad  = ln >> 4;
    int mrow  = blockIdx.x * 64 + w * 16 + lane16;
    int mload = mrow < n ? mrow : n - 1;
    int nchunk = K >> 5;

    floatx4 acc[8];
    #pragma unroll
    for (int t = 0; t < 8; ++t) acc[t] = (floatx4){0.f, 0.f, 0.f, 0.f};

    for (int c = 0; c < nchunk; ++c) {
        half8 a;
        if constexpr (A32) {
            const float* ap = (const float*)Av + (size_t)mload * K + c * 32 + quad * 8;
            float4 v0 = *(const float4*)ap;
            float4 v1 = *(const float4*)(ap + 4);
            a[0] = (_Float16)v0.x; a[1] = (_Float16)v0.y;
            a[2] = (_Float16)v0.z; a[3] = (_Float16)v0.w;
            a[4] = (_Float16)v1.x; a[5] = (_Float16)v1.y;
            a[6] = (_Float16)v1.z; a[7] = (_Float16)v1.w;
        } else {
            const _Float16* ap = (const _Float16*)Av + (size_t)mload * K + c * 32 + quad * 8;
            a = *(const half8*)ap;
        }
        const _Float16* bp = Bsw + ((size_t)(c * 8) * 64 + ln) * 8;
        #pragma unroll
        for (int t = 0; t < 8; ++t) {
            half8 b = *(const half8*)(bp + (size_t)t * 512);
            acc[t] = __builtin_amdgcn_mfma_f32_16x16x32_f16(a, b, acc[t], 0, 0, 0);
        }
    }

    int rbase = blockIdx.x * 64 + w * 16 + quad * 4;
    #pragma unroll
    for (int r = 0; r < 4; ++r) {
        int R = rbase + r;
        if (R < n) {
            float d = dinv[R];
            half8 o;
            #pragma unroll
            for (int t = 0; t < 8; ++t) o[t] = (_Float16)(acc[t][r] * d);
            *(half8*)(Cb + (size_t)R * 128 + lane16 * 8) = o;
        }
    }
}

// One wave per node. Node->wave mapping (template NPW):
//   NPW=1: one node per wave, grid covers n (agg1: max TLP, R13 optimum).
//   NPW=4: 4 CONSECUTIVE nodes/wave, 3125 blocks (agg2: WcT amortized,
//          R16/R17 optimum) + R20 cross-node prefetch: next node's first
//          col quad / self-row / dinv issued under current node's gathers.
// 16 lanes per row (dwordx4), 4 edges per load instr, x4 unroll = 16 rows in
// flight; col indices for iter t+1 prefetched (R13). v_fma_mix accumulate
// (exact). Remainder loop unroll-2, both gathers in flight (R16).
// shfl_xor(16,32) combines the 4 groups.
// Lane (grp,pos): features at stored positions pos*8..pos*8+7 = cols j*16+pos.
// CLS: WcT[c][k] (132-padded) in LDS once per block; h2 row via per-wave LDS;
// lane computes out[c=pos] over grp's 32-k slice then TWO shfl_xor.
template<bool OUT16, bool CLS, int NPW>
__global__ __launch_bounds__(256) void k_agg(const _Float16* __restrict__ xwb,
                                             const float* __restrict__ dinv,
                                             const int* __restrict__ row_ptr,
                                             const int* __restrict__ col,
                                             const float* __restrict__ bp,
                                             void* __restrict__ hout,
                                             const float* __restrict__ Wc,
                                             const float* __restrict__ bc,
                                             float* __restrict__ outp,
                                             int n) {
    __shared__ float WcT[CLS ? 16 * 132 : 1];   // [c][k], pad 132 vs bank aliasing
    __shared__ float h2s[CLS ? 4 * 128 : 1];    // per-wave h2 row

    int wave = threadIdx.x >> 6;
    int ln   = threadIdx.x & 63;
    int grp  = ln >> 4;          // 0..3: which edge of each quad
    int pos  = ln & 15;          // 16B segment within the 256B row

    if constexpr (CLS) {
        // Wc[128][16] row-major -> WcT[c*132 + k]; coalesced global reads.
        for (int t = threadIdx.x; t < 128 * OUT_DIM; t += 256) {
            int k = t >> 4, c = t & 15;
            WcT[c * 132 + k] = Wc[t];
        }
        __syncthreads();         // before any early return (barrier safety)
    }

    const _Float16* xb = xwb + pos * 8;
    float onef = 1.0f;

    // ---- node-independent operands: once per wave ----
    float4 bq0 = *(const float4*)(bp + pos * 8);
    float4 bq1 = *(const float4*)(bp + pos * 8 + 4);
    float bb[8] = {bq0.x, bq0.y, bq0.z, bq0.w, bq1.x, bq1.y, bq1.z, bq1.w};
    float bcv = 0.f;
    if constexpr (CLS) bcv = bc[pos];

    int i0 = (blockIdx.x * 4 + wave) * NPW;
    if (i0 >= n) return;
    int ecarry = row_ptr[i0];            // row_ptr[i] for the first node

    // ---- cross-node pipeline head: node i0's operands (R20) ----
    // col is padded +16 ints, so the speculative quad read is in-bounds
    // even when the node has fewer than 16 edges.
    uint4 usu_n = *(const uint4*)(xb + (size_t)i0 * 128);
    float di_n  = dinv[i0];
    int c0_n = col[ecarry + grp],     c1_n = col[ecarry + grp + 4];
    int c2_n = col[ecarry + grp + 8], c3_n = col[ecarry + grp + 12];

    #pragma unroll 1
    for (int it = 0; it < NPW; ++it) {
        int i = i0 + it;
        if (NPW > 1 && i >= n) break;
        int e0 = ecarry;
        int e1 = row_ptr[i + 1];
        ecarry = e1;                     // becomes next node's e0

        // consume prefetched operands for this node
        uint4 usu = usu_n;
        float di  = di_n;
        int s0 = c0_n, s1 = c1_n, s2 = c2_n, s3 = c3_n;

        // prefetch NEXT node's operands under this node's gathers (R20)
        if (NPW > 1 && it + 1 < NPW && i + 1 < n) {
            usu_n = *(const uint4*)(xb + (size_t)(i + 1) * 128);
            di_n  = dinv[i + 1];
            c0_n = col[e1 + grp];     c1_n = col[e1 + grp + 4];
            c2_n = col[e1 + grp + 8]; c3_n = col[e1 + grp + 12];
        }

        float acc[8];
        #pragma unroll
        for (int j = 0; j < 8; ++j) acc[j] = 0.f;

        int e = e0 + grp;
        if (e + 12 < e1) {
            while (true) {
                int en = e + 16;
                bool more = (en + 12 < e1);
                int t0, t1, t2, t3;
                if (more) {            // prefetch next quad's indices
                    t0 = col[en]; t1 = col[en + 4]; t2 = col[en + 8]; t3 = col[en + 12];
                }
                uint4 u0 = *(const uint4*)(xb + (size_t)s0 * 128);
                uint4 u1 = *(const uint4*)(xb + (size_t)s1 * 128);
                uint4 u2 = *(const uint4*)(xb + (size_t)s2 * 128);
                uint4 u3 = *(const uint4*)(xb + (size_t)s3 * 128);
                accum8(acc, u0, onef);
                accum8(acc, u1, onef);
                accum8(acc, u2, onef);
                accum8(acc, u3, onef);
                e = en;
                if (!more) break;
                s0 = t0; s1 = t1; s2 = t2; s3 = t3;
            }
        }
        // remainder: unroll-2, both gathers in flight (tail ILP)
        for (; e + 4 < e1; e += 8) {
            int sa = col[e], sb = col[e + 4];
            uint4 ua = *(const uint4*)(xb + (size_t)sa * 128);
            uint4 ub = *(const uint4*)(xb + (size_t)sb * 128);
            accum8(acc, ua, onef);
            accum8(acc, ub, onef);
        }
        if (e < e1) {
            int s = col[e];
            uint4 u = *(const uint4*)(xb + (size_t)s * 128);
            accum8(acc, u, onef);
        }

        // combine the 4 groups (lanes xor 16, xor 32)
        #pragma unroll
        for (int j = 0; j < 8; ++j) {
            acc[j] += __shfl_xor(acc[j], 16, 64);
            acc[j] += __shfl_xor(acc[j], 32, 64);
        }

        // self-loop (exact fp16->fp32 fma_mix adds)
        accum8(acc, usu, onef);

        float ov[8];
        #pragma unroll
        for (int j = 0; j < 8; ++j)
            ov[j] = fmaxf(fmaf(di, acc[j], bb[j]), 0.f);

        if constexpr (OUT16) {
            if (grp == 0) {
                half8 o;
                #pragma unroll
                for (int j = 0; j < 8; ++j) o[j] = (_Float16)ov[j];
                *(half8*)((_Float16*)hout + (size_t)i * 128 + pos * 8) = o;
            }
        } else {
            // position p = pos*8+j holds col j*16+pos; all-lane split: grp g
            // stores j=2g,2g+1 -> 2 stores/lane, wave covers the 512B row.
            float* hf = (float*)hout + (size_t)i * 128;
            #pragma unroll
            for (int h = 0; h < 2; ++h) {
                int j = 2 * grp + h;
                hf[j * 16 + pos] = ov[j];
                if constexpr (CLS) h2s[wave * 128 + j * 16 + pos] = ov[j];
            }
        }

        if constexpr (CLS) {
            // out[i][c=pos] = sum_k h2[k] * WcT[pos][k] + bc[pos];
            // lane covers k = grp*32 .. grp*32+31, then reduce over grp.
            // (wave-private LDS: ds ordering within the wave, no barrier)
            const float* wrow = &WcT[pos * 132 + grp * 32];
            const float* hrow = &h2s[wave * 128 + grp * 32];   // broadcast reads
            float pt = 0.f;
            #pragma unroll
            for (int kk = 0; kk < 32; kk += 4) {
                float4 wv = *(const float4*)(wrow + kk);
                float4 hv = *(const float4*)(hrow + kk);
                pt = fmaf(hv.x, wv.x, pt);
                pt = fmaf(hv.y, wv.y, pt);
                pt = fmaf(hv.z, wv.z, pt);
                pt = fmaf(hv.w, wv.w, pt);
            }
            pt += __shfl_xor(pt, 16, 64);
            pt += __shfl_xor(pt, 32, 64);
            if (grp == 0) outp[(size_t)i * OUT_DIM + pos] = pt + bcv;
        }
    }
}

static inline size_t align256(size_t x) { return (x + 255) & ~(size_t)255; }

extern "C" void kernel_launch(void* const* d_in, const int* in_sizes, int n_in,
                              void* d_out, int out_size, void* d_ws, size_t ws_size,
                              hipStream_t stream) {
    const float* fts = (const float*)d_in[0];
    const int*   ei  = (const int*)d_in[1];
    const float* W1  = (const float*)d_in[2];
    const float* b1  = (const float*)d_in[3];
    const float* W2  = (const float*)d_in[4];
    const float* b2  = (const float*)d_in[5];
    const float* Wc  = (const float*)d_in[6];
    const float* bc  = (const float*)d_in[7];

    const int N = in_sizes[0] / IN_DIM;     // 50000
    const int E = in_sizes[1] / 2;          // 800000
    const int* src = ei;
    const int* dst = ei + E;

    char* p = (char*)d_ws;
    int* rep      = (int*)p;               p += align256(sizeof(int) * NREP * N);
    int* deg      = (int*)p;               p += align256(sizeof(int) * N);
    int* row_ptr  = (int*)p;               p += align256(sizeof(int) * (N + 1));
    float* dinv   = (float*)p;             p += align256(sizeof(float) * N);
    int* slot     = (int*)p;               p += align256(sizeof(int) * E);
    int* col      = (int*)p;               p += align256(sizeof(int) * (E + 16));  // +16: speculative quad
    int* bsum     = (int*)p;               p += align256(sizeof(int) * 512);
    _Float16* Bsw1 = (_Float16*)p;         p += align256(sizeof(_Float16) * IN_DIM * HID);
    _Float16* Bsw2 = (_Float16*)p;         p += align256(sizeof(_Float16) * HID * HID);
    float* bp1    = (float*)p;             p += align256(sizeof(float) * HID);
    float* bp2    = (float*)p;             p += align256(sizeof(float) * HID);
    _Float16* xwb = (_Float16*)p;          p += align256(sizeof(_Float16) * (size_t)N * HID);
    _Float16* h1  = (_Float16*)p;          p += align256(sizeof(_Float16) * (size_t)N * HID);

    float* out = (float*)d_out;                   // [N,16]
    float* h2  = (float*)d_out + (size_t)N * 16;  // [N,128]

    const int T = 256;
    const int E8 = E / 8;
    dim3 gE8((E8 + T - 1) / T);
    const int nScanB = (N + SCAN_B - 1) / SCAN_B;

    // Fused prep (rep zero + W swizzles + bias perms)
    const int nrepN = NREP * N;
    const int zr = (nrepN >> 2) + (nrepN & 3);
    const int prepTot = zr + IN_DIM * HID + HID * HID + 2 * HID;
    k_prep<<<(prepTot + T - 1) / T, T, 0, stream>>>(rep, nrepN, W1, Bsw1, W2, Bsw2,
                                                    b1, bp1, b2, bp2);
    // Graph structure
    k_count<<<gE8, T, 0, stream>>>(dst, rep, slot, N, E8, E);
    k_scan1<<<nScanB, SCAN_B, 0, stream>>>(rep, deg, row_ptr, bsum, N, N);
    k_scan3<<<nScanB, SCAN_B, 0, stream>>>(row_ptr, bsum, deg, dinv, rep, N, N, E);
    k_fill<<<gE8, T, 0, stream>>>(src, dst, slot, rep, col, N, E8, E);

    dim3 gGemm((N + 63) / 64);
    dim3 gAgg1((N + 3) / 4);            // NPW=1: 12500 blocks (max TLP)
    dim3 gAgg2((N + 15) / 16);          // NPW=4: 3125 blocks (amortized CLS)

    // Layer 1
    k_gemm_mfma<true><<<gGemm, T, 0, stream>>>(fts, Bsw1, xwb, dinv, N, IN_DIM);
    k_agg<true, false, 1><<<gAgg1, T, 0, stream>>>(xwb, dinv, row_ptr, col, bp1, h1,
                                                   nullptr, nullptr, nullptr, N);
    // Layer 2
    k_gemm_mfma<false><<<gGemm, T, 0, stream>>>(h1, Bsw2, xwb, dinv, N, HID);
    // Aggregation + fused classifier (NPW=4 + cross-node prefetch)
    k_agg<false, true, 4><<<gAgg2, T, 0, stream>>>(xwb, dinv, row_ptr, col, bp2, h2,
                                                   Wc, bc, out, N);
}

// Round 12
// 253.294 us; speedup vs baseline: 1.0320x; 1.0320x over previous
//
#include <hip/hip_runtime.h>

// ---------------------------------------------------------------------------
// GCN: x1 = relu(Ahat @ (fts@W1) + b1); x2 = relu(Ahat @ (x1@W2) + b2);
//      out = x2@Wc + bc.  Ahat = D^-1/2 (A + I) D^-1/2.
// d_out = [out (N*16) | x2 (N*128)] fp32.
// R2: hierarchical scan. R3: gather prescale+unroll. R4: MFMA fp16 GEMMs.
// R5/R6: slot-capture CSR build. R7: 8-replica counters. R8: launch diet.
// R9: barrier-free agg, 16 lanes/row dwordx4 gathers, shfl_xor combine.
// R10 FAILED: persistent fused graph build ran at 1 wave/SIMD (130us).
// R11: split graph build restored; CLS fusion kept (+12us epilogue tax).
// R12: epilogue diet (hoisted operands, LDS WcT, 2-shfl reduce): agg2 53->48.
// R13: v_fma_mix accumulate (1 VALU/elem) + col prefetch: agg2 48.4->47.4.
// R14/15 FAILED: persistent strided agg: occupancy 67->39%, agg2 +2us.
// R16: NPW=4 consecutive + tail unroll-2: agg2 47.4->42.0, agg1 +5us.
// R17: NPW per-kernel: agg1 NPW=1, agg2 NPW=4. BEST: 257.0us.
// R18/19 FAILED: balanced exact-fit split: drain-tail occupancy collapse.
// R20 FAILED: cross-node prefetch: agg2 42->51.8 (+4 VGPR live across the
//      whole gather loop + dependent stall at node head). Reverted.
//      LESSON (R14/R18/R20): don't fight the HW scheduler on this workload.
// R21: scan merge via atomic block-ticket. scan1+scan3 -> ONE k_scan:
//      plane offsets kept in regs (8 stores/node once, was 16+8 loads),
//      block base = atomicAdd(gtick, blockTotal), no bsum round-trip,
//      one less launch. Bases non-monotone across scan-blocks => agg reads
//      explicit row_end[] instead of row_ptr[i+1] (any disjoint per-node
//      range is valid; within-node order unchanged). NPW=4 ecarry still
//      valid: 4 | 256 so a wave's nodes never cross a scan-block.
// ---------------------------------------------------------------------------

#define IN_DIM 256
#define HID 128
#define OUT_DIM 16
#define SCAN_B 256
#define NREP 8

typedef _Float16 half8  __attribute__((ext_vector_type(8)));
typedef float    floatx4 __attribute__((ext_vector_type(4)));

// acc[0..7] += fp16 elements of u (4 dwords, lo/hi halves), exact, 1 VALU each.
__device__ __forceinline__ void accum8(float* acc, uint4 u, float onef) {
    asm("v_fma_mix_f32 %0, %1, %2, %0 op_sel:[0,0,0] op_sel_hi:[1,0,0]"
        : "+v"(acc[0]) : "v"(u.x), "v"(onef));
    asm("v_fma_mix_f32 %0, %1, %2, %0 op_sel:[1,0,0] op_sel_hi:[1,0,0]"
        : "+v"(acc[1]) : "v"(u.x), "v"(onef));
    asm("v_fma_mix_f32 %0, %1, %2, %0 op_sel:[0,0,0] op_sel_hi:[1,0,0]"
        : "+v"(acc[2]) : "v"(u.y), "v"(onef));
    asm("v_fma_mix_f32 %0, %1, %2, %0 op_sel:[1,0,0] op_sel_hi:[1,0,0]"
        : "+v"(acc[3]) : "v"(u.y), "v"(onef));
    asm("v_fma_mix_f32 %0, %1, %2, %0 op_sel:[0,0,0] op_sel_hi:[1,0,0]"
        : "+v"(acc[4]) : "v"(u.z), "v"(onef));
    asm("v_fma_mix_f32 %0, %1, %2, %0 op_sel:[1,0,0] op_sel_hi:[1,0,0]"
        : "+v"(acc[5]) : "v"(u.z), "v"(onef));
    asm("v_fma_mix_f32 %0, %1, %2, %0 op_sel:[0,0,0] op_sel_hi:[1,0,0]"
        : "+v"(acc[6]) : "v"(u.w), "v"(onef));
    asm("v_fma_mix_f32 %0, %1, %2, %0 op_sel:[1,0,0] op_sel_hi:[1,0,0]"
        : "+v"(acc[7]) : "v"(u.w), "v"(onef));
}

__device__ __forceinline__ void wswz_one(const float* W, _Float16* Bsw, int o, int permK) {
    int j    = o & 7;
    int lane = (o >> 3) & 63;
    int t    = (o >> 9) & 7;
    int c    = o >> 12;
    int k = c * 32 + ((lane >> 4) << 3) + j;
    if (permK) k = ((k & 7) << 4) + (k >> 3);
    int ncol = t * 16 + (lane & 15);
    Bsw[o] = (_Float16)W[k * 128 + ncol];
}

// Fused prep: zero rep planes + ticket; swizzle W1,W2; permute biases.
__global__ void k_prep(int* __restrict__ rep, int nrepN, int* __restrict__ gtick,
                       const float* __restrict__ W1, _Float16* __restrict__ Bsw1,
                       const float* __restrict__ W2, _Float16* __restrict__ Bsw2,
                       const float* __restrict__ b1, float* __restrict__ bp1,
                       const float* __restrict__ b2, float* __restrict__ bp2) {
    int t = blockIdx.x * blockDim.x + threadIdx.x;
    if (t == 0) gtick[0] = 0;
    int z4 = nrepN >> 2;
    int zr = z4 + (nrepN & 3);
    if (t < z4) { ((int4*)rep)[t] = make_int4(0, 0, 0, 0); return; }
    if (t < zr) { rep[4 * z4 + (t - z4)] = 0; return; }
    int o = t - zr;
    if (o < IN_DIM * HID) { wswz_one(W1, Bsw1, o, 0); return; }
    o -= IN_DIM * HID;
    if (o < HID * HID) { wswz_one(W2, Bsw2, o, 1); return; }
    o -= HID * HID;
    if (o < HID) { bp1[o] = b1[((o & 7) << 4) + (o >> 3)]; return; }
    o -= HID;
    if (o < HID) { bp2[o] = b2[((o & 7) << 4) + (o >> 3)]; return; }
}

// Thread i owns edges 8i..8i+7; edge 8i+k bumps replica plane k.
__global__ void k_count(const int* __restrict__ dst, int* __restrict__ rep,
                        int* __restrict__ slot, int nN, int e8, int e) {
    int i = blockIdx.x * blockDim.x + threadIdx.x;
    if (i < e8) {
        int4 d0 = ((const int4*)dst)[2 * i];
        int4 d1 = ((const int4*)dst)[2 * i + 1];
        int4 s0, s1;
        s0.x = atomicAdd(&rep[0 * nN + d0.x], 1);
        s0.y = atomicAdd(&rep[1 * nN + d0.y], 1);
        s0.z = atomicAdd(&rep[2 * nN + d0.z], 1);
        s0.w = atomicAdd(&rep[3 * nN + d0.w], 1);
        s1.x = atomicAdd(&rep[4 * nN + d1.x], 1);
        s1.y = atomicAdd(&rep[5 * nN + d1.y], 1);
        s1.z = atomicAdd(&rep[6 * nN + d1.z], 1);
        s1.w = atomicAdd(&rep[7 * nN + d1.w], 1);
        ((int4*)slot)[2 * i]     = s0;
        ((int4*)slot)[2 * i + 1] = s1;
    }
    int base = e8 * 8;
    int t = blockIdx.x * blockDim.x + threadIdx.x;
    if (t < e - base) {
        int j = base + t;
        slot[j] = atomicAdd(&rep[(j & 7) * nN + dst[j]], 1);
    }
}

// Merged scan (R21): plane offsets in regs -> LDS scan of node totals ->
// block base via atomic ticket -> write row_beg/row_end/dinv + baked planes.
// Bases are non-monotone across blocks (valid: ranges disjoint & exact).
__global__ __launch_bounds__(SCAN_B) void k_scan(int* __restrict__ rep,
                                                 int* __restrict__ row_beg,
                                                 int* __restrict__ row_end,
                                                 float* __restrict__ dinv,
                                                 int* __restrict__ gtick,
                                                 int nN, int n) {
    __shared__ int tmp[SCAN_B];
    __shared__ int sbase;
    int tid = threadIdx.x;
    int i = blockIdx.x * SCAN_B + tid;
    int off[NREP];
    int c = 0;
    if (i < n) {
        #pragma unroll
        for (int r = 0; r < NREP; ++r) {
            int t = rep[r * nN + i];
            off[r] = c;
            c += t;
        }
    }
    tmp[tid] = c;
    __syncthreads();
    #pragma unroll
    for (int o = 1; o < SCAN_B; o <<= 1) {
        int v = (tid >= o) ? tmp[tid - o] : 0;
        __syncthreads();
        tmp[tid] += v;
        __syncthreads();
    }
    if (tid == SCAN_B - 1) sbase = atomicAdd(gtick, tmp[tid]);
    __syncthreads();
    int base = sbase;
    if (i < n) {
        int rp = base + tmp[tid] - c;
        row_beg[i] = rp;
        row_end[i] = rp + c;
        dinv[i] = rsqrtf((float)(c + 1));   // +1 self-loop
        #pragma unroll
        for (int r = 0; r < NREP; ++r) rep[r * nN + i] = off[r] + rp;
    }
}

// Atomic-free scatter: col[rep[k][dst] + slot] = src.
__global__ void k_fill(const int* __restrict__ src, const int* __restrict__ dst,
                       const int* __restrict__ slot, const int* __restrict__ rep,
                       int* __restrict__ col, int nN, int e8, int e) {
    int i = blockIdx.x * blockDim.x + threadIdx.x;
    if (i < e8) {
        int4 v0 = ((const int4*)src)[2 * i];
        int4 v1 = ((const int4*)src)[2 * i + 1];
        int4 d0 = ((const int4*)dst)[2 * i];
        int4 d1 = ((const int4*)dst)[2 * i + 1];
        int4 s0 = ((const int4*)slot)[2 * i];
        int4 s1 = ((const int4*)slot)[2 * i + 1];
        col[rep[0 * nN + d0.x] + s0.x] = v0.x;
        col[rep[1 * nN + d0.y] + s0.y] = v0.y;
        col[rep[2 * nN + d0.z] + s0.z] = v0.z;
        col[rep[3 * nN + d0.w] + s0.w] = v0.w;
        col[rep[4 * nN + d1.x] + s1.x] = v1.x;
        col[rep[5 * nN + d1.y] + s1.y] = v1.y;
        col[rep[6 * nN + d1.z] + s1.z] = v1.z;
        col[rep[7 * nN + d1.w] + s1.w] = v1.w;
    }
    int base = e8 * 8;
    int t = blockIdx.x * blockDim.x + threadIdx.x;
    if (t < e - base) {
        int j = base + t;
        col[rep[(j & 7) * nN + dst[j]] + slot[j]] = src[j];
    }
}

// Cb[n,128](fp16, pi-permuted cols) = dinv[row] * (A[n,K] @ W[K,128]).
template<bool A32>
__global__ __launch_bounds__(256) void k_gemm_mfma(const void* __restrict__ Av,
                                                   const _Float16* __restrict__ Bsw,
                                                   _Float16* __restrict__ Cb,
                                                   const float* __restrict__ dinv,
                                                   int n, int K) {
    int tid   = threadIdx.x;
    int w     = tid >> 6;
    int ln    = tid & 63;
    int lane16 = ln & 15;
    int quad  = ln >> 4;
    int mrow  = blockIdx.x * 64 + w * 16 + lane16;
    int mload = mrow < n ? mrow : n - 1;
    int nchunk = K >> 5;

    floatx4 acc[8];
    #pragma unroll
    for (int t = 0; t < 8; ++t) acc[t] = (floatx4){0.f, 0.f, 0.f, 0.f};

    for (int c = 0; c < nchunk; ++c) {
        half8 a;
        if constexpr (A32) {
            const float* ap = (const float*)Av + (size_t)mload * K + c * 32 + quad * 8;
            float4 v0 = *(const float4*)ap;
            float4 v1 = *(const float4*)(ap + 4);
            a[0] = (_Float16)v0.x; a[1] = (_Float16)v0.y;
            a[2] = (_Float16)v0.z; a[3] = (_Float16)v0.w;
            a[4] = (_Float16)v1.x; a[5] = (_Float16)v1.y;
            a[6] = (_Float16)v1.z; a[7] = (_Float16)v1.w;
        } else {
            const _Float16* ap = (const _Float16*)Av + (size_t)mload * K + c * 32 + quad * 8;
            a = *(const half8*)ap;
        }
        const _Float16* bp = Bsw + ((size_t)(c * 8) * 64 + ln) * 8;
        #pragma unroll
        for (int t = 0; t < 8; ++t) {
            half8 b = *(const half8*)(bp + (size_t)t * 512);
            acc[t] = __builtin_amdgcn_mfma_f32_16x16x32_f16(a, b, acc[t], 0, 0, 0);
        }
    }

    int rbase = blockIdx.x * 64 + w * 16 + quad * 4;
    #pragma unroll
    for (int r = 0; r < 4; ++r) {
        int R = rbase + r;
        if (R < n) {
            float d = dinv[R];
            half8 o;
            #pragma unroll
            for (int t = 0; t < 8; ++t) o[t] = (_Float16)(acc[t][r] * d);
            *(half8*)(Cb + (size_t)R * 128 + lane16 * 8) = o;
        }
    }
}

// One wave per node. Node->wave mapping (template NPW):
//   NPW=1: one node per wave, grid covers n (agg1: max TLP, R13 optimum).
//   NPW=4: 4 CONSECUTIVE nodes/wave, 3125 blocks (agg2: WcT amortized,
//          R16/R17 optimum). Extent via row_beg/row_end (R21: bases
//          non-monotone across scan-blocks; ecarry valid since 4|256).
// 16 lanes per row (dwordx4), 4 edges per load instr, x4 unroll = 16 rows in
// flight; col indices for iter t+1 prefetched (R13). v_fma_mix accumulate
// (exact). Remainder loop unroll-2, both gathers in flight (R16).
// shfl_xor(16,32) combines the 4 groups.
// Lane (grp,pos): features at stored positions pos*8..pos*8+7 = cols j*16+pos.
// CLS: WcT[c][k] (132-padded) in LDS once per block; h2 row via per-wave LDS;
// lane computes out[c=pos] over grp's 32-k slice then TWO shfl_xor.
template<bool OUT16, bool CLS, int NPW>
__global__ __launch_bounds__(256) void k_agg(const _Float16* __restrict__ xwb,
                                             const float* __restrict__ dinv,
                                             const int* __restrict__ row_beg,
                                             const int* __restrict__ row_end,
                                             const int* __restrict__ col,
                                             const float* __restrict__ bp,
                                             void* __restrict__ hout,
                                             const float* __restrict__ Wc,
                                             const float* __restrict__ bc,
                                             float* __restrict__ outp,
                                             int n) {
    __shared__ float WcT[CLS ? 16 * 132 : 1];   // [c][k], pad 132 vs bank aliasing
    __shared__ float h2s[CLS ? 4 * 128 : 1];    // per-wave h2 row

    int wave = threadIdx.x >> 6;
    int ln   = threadIdx.x & 63;
    int grp  = ln >> 4;          // 0..3: which edge of each quad
    int pos  = ln & 15;          // 16B segment within the 256B row

    if constexpr (CLS) {
        // Wc[128][16] row-major -> WcT[c*132 + k]; coalesced global reads.
        for (int t = threadIdx.x; t < 128 * OUT_DIM; t += 256) {
            int k = t >> 4, c = t & 15;
            WcT[c * 132 + k] = Wc[t];
        }
        __syncthreads();         // before any early return (barrier safety)
    }

    const _Float16* xb = xwb + pos * 8;
    float onef = 1.0f;

    // ---- node-independent operands: once per wave ----
    float4 bq0 = *(const float4*)(bp + pos * 8);
    float4 bq1 = *(const float4*)(bp + pos * 8 + 4);
    float bb[8] = {bq0.x, bq0.y, bq0.z, bq0.w, bq1.x, bq1.y, bq1.z, bq1.w};
    float bcv = 0.f;
    if constexpr (CLS) bcv = bc[pos];

    int i0 = (blockIdx.x * 4 + wave) * NPW;
    if (i0 >= n) return;
    int ecarry = row_beg[i0];            // row_beg[i] for the first node

    #pragma unroll 1
    for (int it = 0; it < NPW; ++it) {
        int i = i0 + it;
        if (NPW > 1 && i >= n) break;
        int e0 = ecarry;
        int e1 = row_end[i];
        ecarry = e1;                     // == row_beg[i+1] within a scan-block

        // self-row + dinv issued before the gather chain
        uint4 usu = *(const uint4*)(xb + (size_t)i * 128);
        float di  = dinv[i];

        float acc[8];
        #pragma unroll
        for (int j = 0; j < 8; ++j) acc[j] = 0.f;

        int e = e0 + grp;
        if (e + 12 < e1) {
            int s0 = col[e], s1 = col[e + 4], s2 = col[e + 8], s3 = col[e + 12];
            while (true) {
                int en = e + 16;
                bool more = (en + 12 < e1);
                int t0, t1, t2, t3;
                if (more) {            // prefetch next quad's indices
                    t0 = col[en]; t1 = col[en + 4]; t2 = col[en + 8]; t3 = col[en + 12];
                }
                uint4 u0 = *(const uint4*)(xb + (size_t)s0 * 128);
                uint4 u1 = *(const uint4*)(xb + (size_t)s1 * 128);
                uint4 u2 = *(const uint4*)(xb + (size_t)s2 * 128);
                uint4 u3 = *(const uint4*)(xb + (size_t)s3 * 128);
                accum8(acc, u0, onef);
                accum8(acc, u1, onef);
                accum8(acc, u2, onef);
                accum8(acc, u3, onef);
                e = en;
                if (!more) break;
                s0 = t0; s1 = t1; s2 = t2; s3 = t3;
            }
        }
        // remainder: unroll-2, both gathers in flight (tail ILP)
        for (; e + 4 < e1; e += 8) {
            int sa = col[e], sb = col[e + 4];
            uint4 ua = *(const uint4*)(xb + (size_t)sa * 128);
            uint4 ub = *(const uint4*)(xb + (size_t)sb * 128);
            accum8(acc, ua, onef);
            accum8(acc, ub, onef);
        }
        if (e < e1) {
            int s = col[e];
            uint4 u = *(const uint4*)(xb + (size_t)s * 128);
            accum8(acc, u, onef);
        }

        // combine the 4 groups (lanes xor 16, xor 32)
        #pragma unroll
        for (int j = 0; j < 8; ++j) {
            acc[j] += __shfl_xor(acc[j], 16, 64);
            acc[j] += __shfl_xor(acc[j], 32, 64);
        }

        // self-loop (exact fp16->fp32 fma_mix adds)
        accum8(acc, usu, onef);

        float ov[8];
        #pragma unroll
        for (int j = 0; j < 8; ++j)
            ov[j] = fmaxf(fmaf(di, acc[j], bb[j]), 0.f);

        if constexpr (OUT16) {
            if (grp == 0) {
                half8 o;
                #pragma unroll
                for (int j = 0; j < 8; ++j) o[j] = (_Float16)ov[j];
                *(half8*)((_Float16*)hout + (size_t)i * 128 + pos * 8) = o;
            }
        } else {
            // position p = pos*8+j holds col j*16+pos; all-lane split: grp g
            // stores j=2g,2g+1 -> 2 stores/lane, wave covers the 512B row.
            float* hf = (float*)hout + (size_t)i * 128;
            #pragma unroll
            for (int h = 0; h < 2; ++h) {
                int j = 2 * grp + h;
                hf[j * 16 + pos] = ov[j];
                if constexpr (CLS) h2s[wave * 128 + j * 16 + pos] = ov[j];
            }
        }

        if constexpr (CLS) {
            // out[i][c=pos] = sum_k h2[k] * WcT[pos][k] + bc[pos];
            // lane covers k = grp*32 .. grp*32+31, then reduce over grp.
            // (wave-private LDS: ds ordering within the wave, no barrier)
            const float* wrow = &WcT[pos * 132 + grp * 32];
            const float* hrow = &h2s[wave * 128 + grp * 32];   // broadcast reads
            float pt = 0.f;
            #pragma unroll
            for (int kk = 0; kk < 32; kk += 4) {
                float4 wv = *(const float4*)(wrow + kk);
                float4 hv = *(const float4*)(hrow + kk);
                pt = fmaf(hv.x, wv.x, pt);
                pt = fmaf(hv.y, wv.y, pt);
                pt = fmaf(hv.z, wv.z, pt);
                pt = fmaf(hv.w, wv.w, pt);
            }
            pt += __shfl_xor(pt, 16, 64);
            pt += __shfl_xor(pt, 32, 64);
            if (grp == 0) outp[(size_t)i * OUT_DIM + pos] = pt + bcv;
        }
    }
}

static inline size_t align256(size_t x) { return (x + 255) & ~(size_t)255; }

extern "C" void kernel_launch(void* const* d_in, const int* in_sizes, int n_in,
                              void* d_out, int out_size, void* d_ws, size_t ws_size,
                              hipStream_t stream) {
    const float* fts = (const float*)d_in[0];
    const int*   ei  = (const int*)d_in[1];
    const float* W1  = (const float*)d_in[2];
    const float* b1  = (const float*)d_in[3];
    const float* W2  = (const float*)d_in[4];
    const float* b2  = (const float*)d_in[5];
    const float* Wc  = (const float*)d_in[6];
    const float* bc  = (const float*)d_in[7];

    const int N = in_sizes[0] / IN_DIM;     // 50000
    const int E = in_sizes[1] / 2;          // 800000
    const int* src = ei;
    const int* dst = ei + E;

    char* p = (char*)d_ws;
    int* rep      = (int*)p;               p += align256(sizeof(int) * NREP * N);
    int* row_beg  = (int*)p;               p += align256(sizeof(int) * N);
    int* row_end  = (int*)p;               p += align256(sizeof(int) * N);
    float* dinv   = (float*)p;             p += align256(sizeof(float) * N);
    int* slot     = (int*)p;               p += align256(sizeof(int) * E);
    int* col      = (int*)p;               p += align256(sizeof(int) * (E + 16));
    int* gtick    = (int*)p;               p += align256(sizeof(int) * 16);
    _Float16* Bsw1 = (_Float16*)p;         p += align256(sizeof(_Float16) * IN_DIM * HID);
    _Float16* Bsw2 = (_Float16*)p;         p += align256(sizeof(_Float16) * HID * HID);
    float* bp1    = (float*)p;             p += align256(sizeof(float) * HID);
    float* bp2    = (float*)p;             p += align256(sizeof(float) * HID);
    _Float16* xwb = (_Float16*)p;          p += align256(sizeof(_Float16) * (size_t)N * HID);
    _Float16* h1  = (_Float16*)p;          p += align256(sizeof(_Float16) * (size_t)N * HID);

    float* out = (float*)d_out;                   // [N,16]
    float* h2  = (float*)d_out + (size_t)N * 16;  // [N,128]

    const int T = 256;
    const int E8 = E / 8;
    dim3 gE8((E8 + T - 1) / T);
    const int nScanB = (N + SCAN_B - 1) / SCAN_B;

    // Fused prep (rep+ticket zero + W swizzles + bias perms)
    const int nrepN = NREP * N;
    const int zr = (nrepN >> 2) + (nrepN & 3);
    const int prepTot = zr + IN_DIM * HID + HID * HID + 2 * HID;
    k_prep<<<(prepTot + T - 1) / T, T, 0, stream>>>(rep, nrepN, gtick, W1, Bsw1, W2, Bsw2,
                                                    b1, bp1, b2, bp2);
    // Graph structure (count -> merged scan -> fill)
    k_count<<<gE8, T, 0, stream>>>(dst, rep, slot, N, E8, E);
    k_scan<<<nScanB, SCAN_B, 0, stream>>>(rep, row_beg, row_end, dinv, gtick, N, N);
    k_fill<<<gE8, T, 0, stream>>>(src, dst, slot, rep, col, N, E8, E);

    dim3 gGemm((N + 63) / 64);
    dim3 gAgg1((N + 3) / 4);            // NPW=1: 12500 blocks (max TLP)
    dim3 gAgg2((N + 15) / 16);          // NPW=4: 3125 blocks (amortized CLS)

    // Layer 1
    k_gemm_mfma<true><<<gGemm, T, 0, stream>>>(fts, Bsw1, xwb, dinv, N, IN_DIM);
    k_agg<true, false, 1><<<gAgg1, T, 0, stream>>>(xwb, dinv, row_beg, row_end, col,
                                                   bp1, h1, nullptr, nullptr, nullptr, N);
    // Layer 2
    k_gemm_mfma<false><<<gGemm, T, 0, stream>>>(h1, Bsw2, xwb, dinv, N, HID);
    // Aggregation + fused classifier
    k_agg<false, true, 4><<<gAgg2, T, 0, stream>>>(xwb, dinv, row_beg, row_end, col,
                                                   bp2, h2, Wc, bc, out, N);
}